// Round 13
// baseline (608.556 us; speedup 1.0000x reference)
//
#include <hip/hip_runtime.h>

#define S_LEN 2048
#define HDIM 4096
#define NHEADS 32
#define HEAD_DIM 128
#define HALF_DIM 64
#define N_QKV 12288
#define QK_COLS 8192

typedef __attribute__((ext_vector_type(8))) short short8;
typedef __attribute__((ext_vector_type(4))) float f32x4;

typedef const __attribute__((address_space(1))) unsigned int gu32;
typedef __attribute__((address_space(3))) unsigned int lu32;

__device__ __forceinline__ void gload_lds16(const void* g, void* l) {
    __builtin_amdgcn_global_load_lds((gu32*)g, (lu32*)l, 16, 0, 0);
}

__device__ __forceinline__ unsigned short f2bf(float f) {
    unsigned int u = __float_as_uint(f);
    u += 0x7fff + ((u >> 16) & 1);
    return (unsigned short)(u >> 16);
}

__device__ __forceinline__ float bf2f(unsigned short b) {
    return __uint_as_float((unsigned int)b << 16);
}

// XCD-chunked block remap (bx-fast within each XCD's contiguous chunk).
__device__ __forceinline__ void xcd_map(int& bx, int& by) {
    int gx = gridDim.x;
    int lin = blockIdx.y * gx + blockIdx.x;
    int x = lin & 7, c = lin >> 3;
    int bxp = gx >> 3;  // gridDim.x must be a multiple of 8
    bx = bxp * x + c % bxp;
    by = c / bxp;
}

// ---------- conversion kernels ----------

__global__ __launch_bounds__(256) void cvt_hs_k(const float* __restrict__ in,
                                                unsigned short* __restrict__ out, int n4) {
    int i = blockIdx.x * 256 + threadIdx.x;
    if (i >= n4) return;
    float4 v = reinterpret_cast<const float4*>(in)[i];
    ushort4 o;
    o.x = f2bf(v.x); o.y = f2bf(v.y); o.z = f2bf(v.z); o.w = f2bf(v.w);
    reinterpret_cast<ushort4*>(out)[i] = o;
}

// column permutation for q/k sections: puts RoPE partner (d, d+64) 16 cols apart.
__device__ __forceinline__ int permute_col(int n) {
    if (n < QK_COLS) {
        int hd = n & 127;
        int base = n - hd;
        int e = hd & 63;
        int d2 = (e & 15) + 32 * (e >> 4) + ((hd >> 6) << 4);
        return base + d2;
    }
    return n;
}

// in: [R][C] fp32  ->  out: [perm(C)][R] bf16
template <bool PERM>
__global__ __launch_bounds__(256) void tconv_k(const float* __restrict__ in,
                                               unsigned short* __restrict__ out, int R, int C) {
    __shared__ float tile[64][65];
    int c0 = blockIdx.x * 64, r0 = blockIdx.y * 64;
    int tx = threadIdx.x & 63, ty = threadIdx.x >> 6;
#pragma unroll
    for (int i = 0; i < 16; ++i) {
        int r = ty + i * 4;
        tile[r][tx] = in[(size_t)(r0 + r) * C + c0 + tx];
    }
    __syncthreads();
#pragma unroll
    for (int i = 0; i < 16; ++i) {
        int c = ty + i * 4;
        int n = PERM ? permute_col(c0 + c) : (c0 + c);
        out[(size_t)n * R + r0 + tx] = f2bf(tile[tx][c]);
    }
}

// cos/sin tables: [S][64]
__global__ __launch_bounds__(256) void rope_tab_k(const int* __restrict__ pos_raw,
                                                  float* __restrict__ ctab,
                                                  float* __restrict__ stab) {
    int i = blockIdx.x * 256 + threadIdx.x;  // i < S*64
    int s = i >> 6, d = i & 63;
    bool is64 = (pos_raw[1] == 0 && pos_raw[2] == 1);
    int p = is64 ? pos_raw[2 * s] : pos_raw[s];
    const float INVB = -0.14391156831212787f;  // -2*ln(10000)/128
    float freq = expf((float)d * INVB);
    float th = (float)p * freq;
    ctab[i] = cosf(th);
    stab[i] = sinf(th);
}

// ---------- GEMM mainloop (m97-style): 128x128 tile, BK=64, 4 waves (2x2), wave tile 64x64 ----

__device__ __forceinline__ void mainloop(const unsigned short* __restrict__ Ag,
                                         const unsigned short* __restrict__ Bg,
                                         int K, int m0, int n0,
                                         char* As, char* Bs,
                                         f32x4 (&acc)[4][4]) {
    const int tid = threadIdx.x;
    const int wid = tid >> 6, lane = tid & 63, l15 = lane & 15, l4 = lane >> 4;
    const int wm = wid >> 1, wn = wid & 1;
    const int NT = K >> 6;

    size_t abase[4], bbase[4];
    int off[4];
#pragma unroll
    for (int i = 0; i < 4; ++i) {
        int p = (i * 256 + tid) << 4;           // LDS byte offset 0..16383
        int q = p ^ (((p >> 7) & 7) << 4);      // inverse swizzle on global source
        abase[i] = (size_t)(m0 + (q >> 7)) * K + ((q & 127) >> 1);
        bbase[i] = (size_t)(n0 + (q >> 7)) * K + ((q & 127) >> 1);
        off[i] = p;
    }

    for (int t = 0; t < NT; ++t) {
        int k0 = t << 6;
#pragma unroll
        for (int i = 0; i < 4; ++i) gload_lds16(Ag + abase[i] + k0, As + off[i]);
#pragma unroll
        for (int i = 0; i < 4; ++i) gload_lds16(Bg + bbase[i] + k0, Bs + off[i]);
        asm volatile("s_waitcnt vmcnt(0)" ::: "memory");
        __builtin_amdgcn_s_barrier();

        short8 a[4][2], b[4][2];
#pragma unroll
        for (int am = 0; am < 4; ++am)
#pragma unroll
            for (int ks = 0; ks < 2; ++ks) {
                int lin = ((wm * 64 + am * 16 + l15) << 7) + ks * 64 + l4 * 16;
                a[am][ks] = *(const short8*)(As + (lin ^ (((lin >> 7) & 7) << 4)));
            }
#pragma unroll
        for (int bn = 0; bn < 4; ++bn)
#pragma unroll
            for (int ks = 0; ks < 2; ++ks) {
                int lin = ((wn * 64 + bn * 16 + l15) << 7) + ks * 64 + l4 * 16;
                b[bn][ks] = *(const short8*)(Bs + (lin ^ (((lin >> 7) & 7) << 4)));
            }
#pragma unroll
        for (int ks = 0; ks < 2; ++ks)
#pragma unroll
            for (int am = 0; am < 4; ++am)
#pragma unroll
                for (int bn = 0; bn < 4; ++bn)
                    acc[am][bn] = __builtin_amdgcn_mfma_f32_16x16x32_bf16(a[am][ks], b[bn][ks], acc[am][bn], 0, 0, 0);

        __builtin_amdgcn_s_barrier();  // all reads done before next stage overwrites
    }
}

// GEMM1: qkv = hs @ W_qkv (q/k cols permuted), fused RoPE epilogue.
// q outputs are pre-scaled by 1/sqrt(HEAD_DIM) so flash skips the mult.
__global__ __launch_bounds__(256, 3) void gemm1_k(const unsigned short* __restrict__ A,
                                                  const unsigned short* __restrict__ Bt,
                                                  const float* __restrict__ ctab,
                                                  const float* __restrict__ stab,
                                                  unsigned short* __restrict__ qb,
                                                  unsigned short* __restrict__ kb,
                                                  unsigned short* __restrict__ vt) {
    __shared__ __attribute__((aligned(16))) char As[16384];
    __shared__ __attribute__((aligned(16))) char Bs[16384];

    int bx, by;
    xcd_map(bx, by);
    int m0 = by * 128, n0 = bx * 128;

    f32x4 acc[4][4];
#pragma unroll
    for (int i = 0; i < 4; ++i)
#pragma unroll
        for (int j = 0; j < 4; ++j) acc[i][j] = (f32x4){0.f, 0.f, 0.f, 0.f};

    mainloop(A, Bt, HDIM, m0, n0, As, Bs, acc);

    int tid = threadIdx.x, wid = tid >> 6, lane = tid & 63, l15 = lane & 15, l4 = lane >> 4;
    int wm = wid >> 1, wn = wid & 1;
    int which = n0 >> 12;  // 0=q 1=k 2=v
    int head = (n0 & 4095) >> 7;
    if (which < 2) {
        unsigned short* dst = which ? kb : qb;
        float qs = which ? 1.0f : 0.08838834764831845f;  // fold 1/sqrt(128) into q
#pragma unroll
        for (int am = 0; am < 4; ++am)
#pragma unroll
            for (int j = 0; j < 4; ++j) {
                int s = m0 + wm * 64 + am * 16 + l4 * 4 + j;
#pragma unroll
                for (int p = 0; p < 2; ++p) {
                    float x1 = acc[am][2 * p][j], x2 = acc[am][2 * p + 1][j];
                    int e = l15 + 16 * (2 * wn + p);
                    float cs = ctab[s * 64 + e] * qs, sn = stab[s * 64 + e] * qs;
                    dst[((size_t)head * S_LEN + s) * HEAD_DIM + e] = f2bf(x1 * cs - x2 * sn);
                    dst[((size_t)head * S_LEN + s) * HEAD_DIM + e + 64] = f2bf(x1 * sn + x2 * cs);
                }
            }
    } else {
#pragma unroll
        for (int am = 0; am < 4; ++am)
#pragma unroll
            for (int j = 0; j < 4; ++j) {
                int s = m0 + wm * 64 + am * 16 + l4 * 4 + j;
#pragma unroll
                for (int bn = 0; bn < 4; ++bn) {
                    int d = wn * 64 + bn * 16 + l15;
                    vt[((size_t)head * HEAD_DIM + d) * S_LEN + s] = f2bf(acc[am][bn][j]);
                }
            }
    }
}

// GEMM2: out = ctx @ W_o (fp32 out)
__global__ __launch_bounds__(256, 3) void gemm2_k(const unsigned short* __restrict__ A,
                                                  const unsigned short* __restrict__ Bt,
                                                  float* __restrict__ out) {
    __shared__ __attribute__((aligned(16))) char As[16384];
    __shared__ __attribute__((aligned(16))) char Bs[16384];

    int bx, by;
    xcd_map(bx, by);
    int m0 = by * 128, n0 = bx * 128;

    f32x4 acc[4][4];
#pragma unroll
    for (int i = 0; i < 4; ++i)
#pragma unroll
        for (int j = 0; j < 4; ++j) acc[i][j] = (f32x4){0.f, 0.f, 0.f, 0.f};

    mainloop(A, Bt, HDIM, m0, n0, As, Bs, acc);

    int tid = threadIdx.x, wid = tid >> 6, lane = tid & 63, l15 = lane & 15, l4 = lane >> 4;
    int wm = wid >> 1, wn = wid & 1;
#pragma unroll
    for (int am = 0; am < 4; ++am)
#pragma unroll
        for (int j = 0; j < 4; ++j) {
            int s = m0 + wm * 64 + am * 16 + l4 * 4 + j;
#pragma unroll
            for (int bn = 0; bn < 4; ++bn)
                out[(size_t)s * HDIM + n0 + wn * 64 + bn * 16 + l15] = acc[am][bn][j];
        }
}

// ---------- flash attention v6: KVBLK=32, dbuf, 40KB LDS -> 4 blocks/CU ----------
// 72 (qblk,spl) slots per head; split span = 256 kv (NT in {4,8} 32-kv tiles).
// Double-buffered K/V (prefetch t+1 then counted vmcnt(4)). bf16 partials + fp32 (m,l).
__global__ __launch_bounds__(256) void flash_k(const unsigned short* __restrict__ Q,
                                               const unsigned short* __restrict__ Kb,
                                               const unsigned short* __restrict__ Vt,
                                               unsigned short* __restrict__ O_parts,
                                               float* __restrict__ ml) {
    __shared__ __attribute__((aligned(16))) char Ks[2][8192];  // [32 kv][128 d] bf16, 256B rows
    __shared__ __attribute__((aligned(16))) char Vs[2][8192];  // [128 d][32 kv] bf16, 64B rows
    __shared__ __attribute__((aligned(16))) char Ps[4][2048];  // per-wave [32 q][32 kv] bf16
    int h = blockIdx.y;
    int s = 71 - (int)blockIdx.x;  // LPT: high-qblk slots dispatch first
    int qblk = 0, spl = 0;
    {
        int st = 0;
        for (int j = 0; j < 16; ++j) {
            int ns = (j >> 1) + 1;
            if (s < st + ns) { qblk = j; spl = s - st; break; }
            st += ns;
        }
    }
    int pidx = h * 72 + s;
    int kv_start = spl << 8;
    int kv_end = min((qblk + 1) << 7, (spl + 1) << 8);
    int NT = (kv_end - kv_start) >> 5;

    int tid = threadIdx.x, w = tid >> 6, lane = tid & 63, l15 = lane & 15, l4 = lane >> 4;
    int qrow0 = qblk * 128 + w * 32;

    const unsigned short* Kg = Kb + (size_t)h * S_LEN * HEAD_DIM;
    const unsigned short* Vg = Vt + (size_t)h * HEAD_DIM * S_LEN;

    short8 qf[2][4];
#pragma unroll
    for (int mt = 0; mt < 2; ++mt) {
        int sr = qrow0 + mt * 16 + l15;
#pragma unroll
        for (int ks = 0; ks < 4; ++ks)
            qf[mt][ks] = *(const short8*)(Q + ((size_t)h * S_LEN + sr) * HEAD_DIM + ks * 32 + l4 * 8);
    }

    float m_run[2][4];
    f32x4 o[2][8];
    f32x4 lsum[2];
#pragma unroll
    for (int mt = 0; mt < 2; ++mt) {
#pragma unroll
        for (int j = 0; j < 4; ++j) m_run[mt][j] = -1e30f;
        lsum[mt] = (f32x4){0.f, 0.f, 0.f, 0.f};
#pragma unroll
        for (int dt = 0; dt < 8; ++dt) o[mt][dt] = (f32x4){0.f, 0.f, 0.f, 0.f};
    }

    // staging offsets: 256 thr x 16B = 4KB/round -> 2 rounds per 8KB buffer
    int lofs[2], kgofs[2], vgofs[2];
#pragma unroll
    for (int i = 0; i < 2; ++i) {
        int p = (i * 256 + tid) << 4;  // [0, 8192)
        lofs[i] = p;
        int qk = p ^ (((p >> 8) & 7) << 4);                       // K: 256B rows, row&7 swizzle
        kgofs[i] = (qk >> 8) * HEAD_DIM + ((qk & 255) >> 1);
        int qv = p ^ (((((p >> 6) & 3) ^ ((p >> 8) & 3)) << 4));  // V: 64B rows, (r&3)^(r>>2&3)
        vgofs[i] = (qv >> 6) * S_LEN + ((qv & 63) >> 1);
    }

    auto stage = [&](int t) {
        char* Kd = Ks[t & 1];
        char* Vd = Vs[t & 1];
        int kvoff = kv_start + t * 32;
#pragma unroll
        for (int i = 0; i < 2; ++i) gload_lds16(Kg + (size_t)kvoff * HEAD_DIM + kgofs[i], Kd + lofs[i]);
#pragma unroll
        for (int i = 0; i < 2; ++i) gload_lds16(Vg + kvoff + vgofs[i], Vd + lofs[i]);
    };

    short8 onesv;
#pragma unroll
    for (int e = 0; e < 8; ++e) onesv[e] = (short)0x3F80;  // bf16 1.0

    stage(0);

    for (int t = 0; t < NT; ++t) {
        int cur = t & 1;
        if (t + 1 < NT) {
            stage(t + 1);
            asm volatile("s_waitcnt vmcnt(4)" ::: "memory");
        } else {
            asm volatile("s_waitcnt vmcnt(0)" ::: "memory");
        }
        __builtin_amdgcn_sched_barrier(0);
        __builtin_amdgcn_s_barrier();
        __builtin_amdgcn_sched_barrier(0);

        // ---- QK^T : 32 q-rows x 32 kv (q pre-scaled by 1/sqrt(d)) ----
        f32x4 sc[2][2];
#pragma unroll
        for (int mt = 0; mt < 2; ++mt)
#pragma unroll
            for (int nt = 0; nt < 2; ++nt) sc[mt][nt] = (f32x4){0.f, 0.f, 0.f, 0.f};
        __builtin_amdgcn_s_setprio(1);
#pragma unroll
        for (int ks = 0; ks < 4; ++ks) {
            short8 kfr[2];
#pragma unroll
            for (int nt = 0; nt < 2; ++nt) {
                int lin = ((nt * 16 + l15) << 8) + ks * 64 + l4 * 16;
                kfr[nt] = *(const short8*)(Ks[cur] + (lin ^ (((lin >> 8) & 7) << 4)));
            }
#pragma unroll
            for (int mt = 0; mt < 2; ++mt)
#pragma unroll
                for (int nt = 0; nt < 2; ++nt)
                    sc[mt][nt] = __builtin_amdgcn_mfma_f32_16x16x32_bf16(qf[mt][ks], kfr[nt], sc[mt][nt], 0, 0, 0);
        }
        __builtin_amdgcn_s_setprio(0);

        // ---- mask + row-max (shuffle reduce), defer-max decision ----
        float pmax[2][4];
        bool need = false;
#pragma unroll
        for (int mt = 0; mt < 2; ++mt)
#pragma unroll
            for (int j = 0; j < 4; ++j) {
                int srow = qrow0 + mt * 16 + l4 * 4 + j;
                int cc = kv_start + t * 32 + l15;
                float v0 = (cc      <= srow) ? sc[mt][0][j] : -1e30f;
                float v1 = (cc + 16 <= srow) ? sc[mt][1][j] : -1e30f;
                sc[mt][0][j] = v0; sc[mt][1][j] = v1;
                float mx = fmaxf(v0, v1);
                mx = fmaxf(mx, __shfl_xor(mx, 1));
                mx = fmaxf(mx, __shfl_xor(mx, 2));
                mx = fmaxf(mx, __shfl_xor(mx, 4));
                mx = fmaxf(mx, __shfl_xor(mx, 8));
                pmax[mt][j] = mx;
                need = need || (mx > m_run[mt][j] + 8.0f);
            }
        if (__any(need ? 1 : 0)) {
#pragma unroll
            for (int mt = 0; mt < 2; ++mt)
#pragma unroll
                for (int j = 0; j < 4; ++j) {
                    float mnew = fmaxf(m_run[mt][j], pmax[mt][j]);
                    float r = __expf(m_run[mt][j] - mnew);
                    m_run[mt][j] = mnew;
                    lsum[mt][j] *= r;
#pragma unroll
                    for (int dt = 0; dt < 8; ++dt) o[mt][dt][j] *= r;
                }
        }

        // ---- P = exp(S - m), write to swizzled per-wave Ps (64B rows) ----
#pragma unroll
        for (int mt = 0; mt < 2; ++mt)
#pragma unroll
            for (int j = 0; j < 4; ++j) {
                int prow = mt * 16 + l4 * 4 + j;
                int rb = prow << 6;
                int sw = (((prow & 3) ^ ((prow >> 2) & 3)) << 4);
#pragma unroll
                for (int nt = 0; nt < 2; ++nt) {
                    unsigned short pb = f2bf(__expf(sc[mt][nt][j] - m_run[mt][j]));
                    *(unsigned short*)(Ps[w] + ((rb + (l15 + nt * 16) * 2) ^ sw)) = pb;
                }
            }
        asm volatile("s_waitcnt lgkmcnt(0)" ::: "memory");
        __builtin_amdgcn_sched_barrier(0);

        // ---- PV + ones-column row-sum ----
        short8 pf[2];
#pragma unroll
        for (int mt = 0; mt < 2; ++mt) {
            int lin = ((mt * 16 + l15) << 6) + l4 * 16;
            pf[mt] = *(const short8*)(Ps[w] + (lin ^ (((((lin >> 6) & 3) ^ ((lin >> 8) & 3)) << 4))));
        }
        __builtin_amdgcn_s_setprio(1);
#pragma unroll
        for (int mt = 0; mt < 2; ++mt)
            lsum[mt] = __builtin_amdgcn_mfma_f32_16x16x32_bf16(pf[mt], onesv, lsum[mt], 0, 0, 0);
#pragma unroll
        for (int dt = 0; dt < 8; ++dt) {
            int lin = ((dt * 16 + l15) << 6) + l4 * 16;
            short8 vf = *(const short8*)(Vs[cur] + (lin ^ (((((lin >> 6) & 3) ^ ((lin >> 8) & 3)) << 4))));
#pragma unroll
            for (int mt = 0; mt < 2; ++mt)
                o[mt][dt] = __builtin_amdgcn_mfma_f32_16x16x32_bf16(pf[mt], vf, o[mt][dt], 0, 0, 0);
        }
        __builtin_amdgcn_s_setprio(0);
        __builtin_amdgcn_sched_barrier(0);
        __builtin_amdgcn_s_barrier();
        __builtin_amdgcn_sched_barrier(0);
    }

    // epilogue: write unnormalized bf16 partial + fp32 (m, l)
    unsigned short* Op = O_parts + (size_t)pidx * 16384;
#pragma unroll
    for (int mt = 0; mt < 2; ++mt)
#pragma unroll
        for (int j = 0; j < 4; ++j) {
            int rloc = w * 32 + mt * 16 + l4 * 4 + j;
#pragma unroll
            for (int dt = 0; dt < 8; ++dt)
                Op[rloc * 128 + dt * 16 + l15] = f2bf(o[mt][dt][j]);
            if (l15 == 0) {
                ml[(size_t)pidx * 256 + rloc] = m_run[mt][j];
                ml[(size_t)pidx * 256 + 128 + rloc] = lsum[mt][j];
            }
        }
}

// merge partials: ctx[qblk*128+row][h*128+d] = sum_s w_s O_s / sum_s w_s l_s
__global__ __launch_bounds__(256) void reduce_k(const unsigned short* __restrict__ Op,
                                                const float* __restrict__ ml,
                                                unsigned short* __restrict__ ctx) {
    int qblk = blockIdx.x, h = blockIdx.y;
    int ns = (qblk >> 1) + 1;
    int p = qblk >> 1;
    int st = p * (p + 1) + ((qblk & 1) ? (p + 1) : 0);
    int p0 = h * 72 + st;
#pragma unroll
    for (int it = 0; it < 16; ++it) {
        int idx = it * 256 + threadIdx.x;
        int row = idx >> 5, dq = idx & 31;
        float mstar = -1e30f;
        for (int s = 0; s < ns; ++s)
            mstar = fmaxf(mstar, ml[(size_t)(p0 + s) * 256 + row]);
        f32x4 acc = (f32x4){0.f, 0.f, 0.f, 0.f};
        float lt = 0.f;
        for (int s = 0; s < ns; ++s) {
            float wgt = __expf(ml[(size_t)(p0 + s) * 256 + row] - mstar);
            lt += wgt * ml[(size_t)(p0 + s) * 256 + 128 + row];
            ushort4 ov = *(const ushort4*)(Op + (size_t)(p0 + s) * 16384 + row * 128 + dq * 4);
            acc[0] += bf2f(ov.x) * wgt;
            acc[1] += bf2f(ov.y) * wgt;
            acc[2] += bf2f(ov.z) * wgt;
            acc[3] += bf2f(ov.w) * wgt;
        }
        float inv = 1.0f / lt;
        int grow = qblk * 128 + row;
        ushort4 o4;
        o4.x = f2bf(acc[0] * inv);
        o4.y = f2bf(acc[1] * inv);
        o4.z = f2bf(acc[2] * inv);
        o4.w = f2bf(acc[3] * inv);
        *(ushort4*)(ctx + (size_t)grow * HDIM + h * 128 + dq * 4) = o4;
    }
}

// ---------- launcher ----------

extern "C" void kernel_launch(void* const* d_in, const int* in_sizes, int n_in,
                              void* d_out, int out_size, void* d_ws, size_t ws_size,
                              hipStream_t stream) {
    const float* hs = (const float*)d_in[0];
    const float* wqkv = (const float*)d_in[1];
    const float* wo = (const float*)d_in[2];
    const int* pos = (const int*)d_in[4];
    float* out = (float*)d_out;
    char* ws = (char*)d_ws;
    const size_t MB = 1024 * 1024;

    unsigned short* hs_b = (unsigned short*)(ws);             // 16 MiB
    unsigned short* wq_t = (unsigned short*)(ws + 16 * MB);   // 96 MiB  [12288][4096] (q/k cols permuted)
    unsigned short* wo_t = (unsigned short*)(ws + 112 * MB);  // 32 MiB  [4096][4096]
    unsigned short* qbuf = (unsigned short*)(ws + 144 * MB);  // 16 MiB  [NH][S][HD]
    unsigned short* kbuf = (unsigned short*)(ws + 160 * MB);  // 16 MiB
    unsigned short* vtb  = (unsigned short*)(ws + 176 * MB);  // 16 MiB  [NH][HD][S]
    unsigned short* ctx  = (unsigned short*)(ws + 192 * MB);  // 16 MiB  [S][H]
    float* ctab = (float*)(ws + 208 * MB);                    // 512 KiB
    float* stab = (float*)(ws + 209 * MB);                    // 512 KiB
    // flash partials overlay the wq_t region (dead after gemm1; stream-ordered)
    unsigned short* O_parts = (unsigned short*)(ws + 16 * MB);  // 2304*16384*2B = 75.5 MiB
    float* ml_buf = (float*)(ws + 96 * MB);                     // 2304*256*4B = 2.4 MiB

    cvt_hs_k<<<(S_LEN * HDIM / 4 + 255) / 256, 256, 0, stream>>>(hs, hs_b, S_LEN * HDIM / 4);
    tconv_k<true><<<dim3(N_QKV / 64, HDIM / 64), 256, 0, stream>>>(wqkv, wq_t, HDIM, N_QKV);
    tconv_k<false><<<dim3(HDIM / 64, HDIM / 64), 256, 0, stream>>>(wo, wo_t, HDIM, HDIM);
    rope_tab_k<<<(S_LEN * 64) / 256, 256, 0, stream>>>(pos, ctab, stab);
    gemm1_k<<<dim3(N_QKV / 128, S_LEN / 128), 256, 0, stream>>>(hs_b, wq_t, ctab, stab, qbuf, kbuf, vtb);
    flash_k<<<dim3(72, NHEADS), 256, 0, stream>>>(qbuf, kbuf, vtb, O_parts, ml_buf);
    reduce_k<<<dim3(S_LEN / 128, NHEADS), 256, 0, stream>>>(O_parts, ml_buf, ctx);
    gemm2_k<<<dim3(HDIM / 128, S_LEN / 128), 256, 0, stream>>>(ctx, wo_t, out);
}

// Round 14
// 533.131 us; speedup vs baseline: 1.1415x; 1.1415x over previous
//
#include <hip/hip_runtime.h>

#define S_LEN 2048
#define HDIM 4096
#define NHEADS 32
#define HEAD_DIM 128
#define HALF_DIM 64
#define N_QKV 12288
#define QK_COLS 8192

typedef __attribute__((ext_vector_type(8))) short short8;
typedef __attribute__((ext_vector_type(4))) float f32x4;

typedef const __attribute__((address_space(1))) unsigned int gu32;
typedef __attribute__((address_space(3))) unsigned int lu32;

__device__ __forceinline__ void gload_lds16(const void* g, void* l) {
    __builtin_amdgcn_global_load_lds((gu32*)g, (lu32*)l, 16, 0, 0);
}

__device__ __forceinline__ unsigned short f2bf(float f) {
    unsigned int u = __float_as_uint(f);
    u += 0x7fff + ((u >> 16) & 1);
    return (unsigned short)(u >> 16);
}

__device__ __forceinline__ float bf2f(unsigned short b) {
    return __uint_as_float((unsigned int)b << 16);
}

// XCD-chunked block remap (bx-fast within each XCD's contiguous chunk).
__device__ __forceinline__ void xcd_map(int& bx, int& by) {
    int gx = gridDim.x;
    int lin = blockIdx.y * gx + blockIdx.x;
    int x = lin & 7, c = lin >> 3;
    int bxp = gx >> 3;  // gridDim.x must be a multiple of 8
    bx = bxp * x + c % bxp;
    by = c / bxp;
}

// ---------- conversion kernels ----------

__global__ __launch_bounds__(256) void cvt_hs_k(const float* __restrict__ in,
                                                unsigned short* __restrict__ out, int n4) {
    int i = blockIdx.x * 256 + threadIdx.x;
    if (i >= n4) return;
    float4 v = reinterpret_cast<const float4*>(in)[i];
    ushort4 o;
    o.x = f2bf(v.x); o.y = f2bf(v.y); o.z = f2bf(v.z); o.w = f2bf(v.w);
    reinterpret_cast<ushort4*>(out)[i] = o;
}

// column permutation for q/k sections: puts RoPE partner (d, d+64) 16 cols apart.
__device__ __forceinline__ int permute_col(int n) {
    if (n < QK_COLS) {
        int hd = n & 127;
        int base = n - hd;
        int e = hd & 63;
        int d2 = (e & 15) + 32 * (e >> 4) + ((hd >> 6) << 4);
        return base + d2;
    }
    return n;
}

// in: [R][C] fp32  ->  out: [perm(C)][R] bf16
template <bool PERM>
__global__ __launch_bounds__(256) void tconv_k(const float* __restrict__ in,
                                               unsigned short* __restrict__ out, int R, int C) {
    __shared__ float tile[64][65];
    int c0 = blockIdx.x * 64, r0 = blockIdx.y * 64;
    int tx = threadIdx.x & 63, ty = threadIdx.x >> 6;
#pragma unroll
    for (int i = 0; i < 16; ++i) {
        int r = ty + i * 4;
        tile[r][tx] = in[(size_t)(r0 + r) * C + c0 + tx];
    }
    __syncthreads();
#pragma unroll
    for (int i = 0; i < 16; ++i) {
        int c = ty + i * 4;
        int n = PERM ? permute_col(c0 + c) : (c0 + c);
        out[(size_t)n * R + r0 + tx] = f2bf(tile[tx][c]);
    }
}

// cos/sin tables: [S][64]
__global__ __launch_bounds__(256) void rope_tab_k(const int* __restrict__ pos_raw,
                                                  float* __restrict__ ctab,
                                                  float* __restrict__ stab) {
    int i = blockIdx.x * 256 + threadIdx.x;  // i < S*64
    int s = i >> 6, d = i & 63;
    bool is64 = (pos_raw[1] == 0 && pos_raw[2] == 1);
    int p = is64 ? pos_raw[2 * s] : pos_raw[s];
    const float INVB = -0.14391156831212787f;  // -2*ln(10000)/128
    float freq = expf((float)d * INVB);
    float th = (float)p * freq;
    ctab[i] = cosf(th);
    stab[i] = sinf(th);
}

// ---------- GEMM mainloop (m97-style): 128x128 tile, BK=64, 4 waves (2x2), wave tile 64x64 ----
// SINGLE-buffered LDS 32KB -> 3 blocks/CU; stage -> vmcnt(0) -> barrier -> compute -> barrier.

__device__ __forceinline__ void mainloop(const unsigned short* __restrict__ Ag,
                                         const unsigned short* __restrict__ Bg,
                                         int K, int m0, int n0,
                                         char* As, char* Bs,
                                         f32x4 (&acc)[4][4]) {
    const int tid = threadIdx.x;
    const int wid = tid >> 6, lane = tid & 63, l15 = lane & 15, l4 = lane >> 4;
    const int wm = wid >> 1, wn = wid & 1;
    const int NT = K >> 6;

    size_t abase[4], bbase[4];
    int off[4];
#pragma unroll
    for (int i = 0; i < 4; ++i) {
        int p = (i * 256 + tid) << 4;           // LDS byte offset 0..16383
        int q = p ^ (((p >> 7) & 7) << 4);      // inverse swizzle on global source
        abase[i] = (size_t)(m0 + (q >> 7)) * K + ((q & 127) >> 1);
        bbase[i] = (size_t)(n0 + (q >> 7)) * K + ((q & 127) >> 1);
        off[i] = p;
    }

    for (int t = 0; t < NT; ++t) {
        int k0 = t << 6;
#pragma unroll
        for (int i = 0; i < 4; ++i) gload_lds16(Ag + abase[i] + k0, As + off[i]);
#pragma unroll
        for (int i = 0; i < 4; ++i) gload_lds16(Bg + bbase[i] + k0, Bs + off[i]);
        asm volatile("s_waitcnt vmcnt(0)" ::: "memory");
        __builtin_amdgcn_s_barrier();

        short8 a[4][2], b[4][2];
#pragma unroll
        for (int am = 0; am < 4; ++am)
#pragma unroll
            for (int ks = 0; ks < 2; ++ks) {
                int lin = ((wm * 64 + am * 16 + l15) << 7) + ks * 64 + l4 * 16;
                a[am][ks] = *(const short8*)(As + (lin ^ (((lin >> 7) & 7) << 4)));
            }
#pragma unroll
        for (int bn = 0; bn < 4; ++bn)
#pragma unroll
            for (int ks = 0; ks < 2; ++ks) {
                int lin = ((wn * 64 + bn * 16 + l15) << 7) + ks * 64 + l4 * 16;
                b[bn][ks] = *(const short8*)(Bs + (lin ^ (((lin >> 7) & 7) << 4)));
            }
#pragma unroll
        for (int ks = 0; ks < 2; ++ks)
#pragma unroll
            for (int am = 0; am < 4; ++am)
#pragma unroll
                for (int bn = 0; bn < 4; ++bn)
                    acc[am][bn] = __builtin_amdgcn_mfma_f32_16x16x32_bf16(a[am][ks], b[bn][ks], acc[am][bn], 0, 0, 0);

        __builtin_amdgcn_s_barrier();  // all reads done before next stage overwrites
    }
}

// GEMM1: qkv = hs @ W_qkv (q/k cols permuted), fused RoPE epilogue.
// q outputs are pre-scaled by 1/sqrt(HEAD_DIM) so flash skips the mult.
__global__ __launch_bounds__(256, 3) void gemm1_k(const unsigned short* __restrict__ A,
                                                  const unsigned short* __restrict__ Bt,
                                                  const float* __restrict__ ctab,
                                                  const float* __restrict__ stab,
                                                  unsigned short* __restrict__ qb,
                                                  unsigned short* __restrict__ kb,
                                                  unsigned short* __restrict__ vt) {
    __shared__ __attribute__((aligned(16))) char As[16384];
    __shared__ __attribute__((aligned(16))) char Bs[16384];

    int bx, by;
    xcd_map(bx, by);
    int m0 = by * 128, n0 = bx * 128;

    f32x4 acc[4][4];
#pragma unroll
    for (int i = 0; i < 4; ++i)
#pragma unroll
        for (int j = 0; j < 4; ++j) acc[i][j] = (f32x4){0.f, 0.f, 0.f, 0.f};

    mainloop(A, Bt, HDIM, m0, n0, As, Bs, acc);

    int tid = threadIdx.x, wid = tid >> 6, lane = tid & 63, l15 = lane & 15, l4 = lane >> 4;
    int wm = wid >> 1, wn = wid & 1;
    int which = n0 >> 12;  // 0=q 1=k 2=v
    int head = (n0 & 4095) >> 7;
    if (which < 2) {
        unsigned short* dst = which ? kb : qb;
        float qs = which ? 1.0f : 0.08838834764831845f;  // fold 1/sqrt(128) into q
#pragma unroll
        for (int am = 0; am < 4; ++am)
#pragma unroll
            for (int j = 0; j < 4; ++j) {
                int s = m0 + wm * 64 + am * 16 + l4 * 4 + j;
#pragma unroll
                for (int p = 0; p < 2; ++p) {
                    float x1 = acc[am][2 * p][j], x2 = acc[am][2 * p + 1][j];
                    int e = l15 + 16 * (2 * wn + p);
                    float cs = ctab[s * 64 + e] * qs, sn = stab[s * 64 + e] * qs;
                    dst[((size_t)head * S_LEN + s) * HEAD_DIM + e] = f2bf(x1 * cs - x2 * sn);
                    dst[((size_t)head * S_LEN + s) * HEAD_DIM + e + 64] = f2bf(x1 * sn + x2 * cs);
                }
            }
    } else {
#pragma unroll
        for (int am = 0; am < 4; ++am)
#pragma unroll
            for (int j = 0; j < 4; ++j) {
                int s = m0 + wm * 64 + am * 16 + l4 * 4 + j;
#pragma unroll
                for (int bn = 0; bn < 4; ++bn) {
                    int d = wn * 64 + bn * 16 + l15;
                    vt[((size_t)head * HEAD_DIM + d) * S_LEN + s] = f2bf(acc[am][bn][j]);
                }
            }
    }
}

// GEMM2: out = ctx @ W_o (fp32 out)
__global__ __launch_bounds__(256, 3) void gemm2_k(const unsigned short* __restrict__ A,
                                                  const unsigned short* __restrict__ Bt,
                                                  float* __restrict__ out) {
    __shared__ __attribute__((aligned(16))) char As[16384];
    __shared__ __attribute__((aligned(16))) char Bs[16384];

    int bx, by;
    xcd_map(bx, by);
    int m0 = by * 128, n0 = bx * 128;

    f32x4 acc[4][4];
#pragma unroll
    for (int i = 0; i < 4; ++i)
#pragma unroll
        for (int j = 0; j < 4; ++j) acc[i][j] = (f32x4){0.f, 0.f, 0.f, 0.f};

    mainloop(A, Bt, HDIM, m0, n0, As, Bs, acc);

    int tid = threadIdx.x, wid = tid >> 6, lane = tid & 63, l15 = lane & 15, l4 = lane >> 4;
    int wm = wid >> 1, wn = wid & 1;
#pragma unroll
    for (int am = 0; am < 4; ++am)
#pragma unroll
        for (int j = 0; j < 4; ++j) {
            int s = m0 + wm * 64 + am * 16 + l4 * 4 + j;
#pragma unroll
            for (int bn = 0; bn < 4; ++bn)
                out[(size_t)s * HDIM + n0 + wn * 64 + bn * 16 + l15] = acc[am][bn][j];
        }
}

// ---------- flash attention (r7 structure + setprio + bf16 partials) ----------
// 40 (qblk,split) slots per head; split span = 512 kv (max 8 kv64-tiles per block).
// Double-buffered K/V staging (prefetch t+1 issued before counted vmcnt(8)).
// Writes unnormalized bf16 O + per-row fp32 (m, l); reduce_k merges.
__global__ __launch_bounds__(256) void flash_k(const unsigned short* __restrict__ Q,
                                               const unsigned short* __restrict__ Kb,
                                               const unsigned short* __restrict__ Vt,
                                               unsigned short* __restrict__ O_parts,
                                               float* __restrict__ ml) {
    __shared__ __attribute__((aligned(16))) char Ks[2][16384];  // [64 kv][128 d] bf16
    __shared__ __attribute__((aligned(16))) char Vs[2][16384];  // [128 d][64 kv] bf16
    __shared__ __attribute__((aligned(16))) char Ps[4][4096];   // per-wave [32 q][64 kv] bf16
    int h = blockIdx.y;
    int bx2 = 39 - (int)blockIdx.x;  // LPT: long blocks (high qblk) dispatch first
    int qblk, spl;
    if (bx2 < 4)       { qblk = bx2;                 spl = 0; }
    else if (bx2 < 12) { qblk = 4 + ((bx2 - 4) >> 1);  spl = (bx2 - 4) & 1; }
    else if (bx2 < 24) { int u = bx2 - 12; int q3 = u / 3; qblk = 8 + q3; spl = u - 3 * q3; }
    else               { qblk = 12 + ((bx2 - 24) >> 2); spl = (bx2 - 24) & 3; }
    int pidx = h * 40 + bx2;
    int kv_start = spl << 9;
    int kv_end = min((qblk + 1) << 7, (spl + 1) << 9);
    int NT = (kv_end - kv_start) >> 6;

    int tid = threadIdx.x, w = tid >> 6, lane = tid & 63, l15 = lane & 15, l4 = lane >> 4;
    int qrow0 = qblk * 128 + w * 32;

    const unsigned short* Kg = Kb + (size_t)h * S_LEN * HEAD_DIM;
    const unsigned short* Vg = Vt + (size_t)h * HEAD_DIM * S_LEN;

    short8 qf[2][4];
#pragma unroll
    for (int mt = 0; mt < 2; ++mt) {
        int s = qrow0 + mt * 16 + l15;
#pragma unroll
        for (int ks = 0; ks < 4; ++ks)
            qf[mt][ks] = *(const short8*)(Q + ((size_t)h * S_LEN + s) * HEAD_DIM + ks * 32 + l4 * 8);
    }

    float m_run[2][4];
    f32x4 o[2][8];
    f32x4 lsum[2];
#pragma unroll
    for (int mt = 0; mt < 2; ++mt) {
#pragma unroll
        for (int j = 0; j < 4; ++j) m_run[mt][j] = -1e30f;
        lsum[mt] = (f32x4){0.f, 0.f, 0.f, 0.f};
#pragma unroll
        for (int dt = 0; dt < 8; ++dt) o[mt][dt] = (f32x4){0.f, 0.f, 0.f, 0.f};
    }

    int lofs[4];
    size_t kgofs[4], vgofs[4];
#pragma unroll
    for (int i = 0; i < 4; ++i) {
        int p = (i * 256 + tid) << 4;
        lofs[i] = p;
        int qk = p ^ (((p >> 8) & 7) << 4);   // K rows are 256B
        kgofs[i] = (size_t)(qk >> 8) * HEAD_DIM + ((qk & 255) >> 1);
        int qv = p ^ (((p >> 7) & 7) << 4);   // V rows are 128B
        vgofs[i] = (size_t)(qv >> 7) * S_LEN + ((qv & 127) >> 1);
    }

    auto stage = [&](int t) {
        char* Kd = Ks[t & 1];
        char* Vd = Vs[t & 1];
        size_t kvoff = (size_t)(kv_start + t * 64);
#pragma unroll
        for (int i = 0; i < 4; ++i) gload_lds16(Kg + kvoff * HEAD_DIM + kgofs[i], Kd + lofs[i]);
#pragma unroll
        for (int i = 0; i < 4; ++i) gload_lds16(Vg + kvoff + vgofs[i], Vd + lofs[i]);
    };

    short8 onesv;
#pragma unroll
    for (int e = 0; e < 8; ++e) onesv[e] = (short)0x3F80;  // bf16 1.0

    stage(0);

    for (int t = 0; t < NT; ++t) {
        int cur = t & 1;
        if (t + 1 < NT) {
            stage(t + 1);
            asm volatile("s_waitcnt vmcnt(8)" ::: "memory");
        } else {
            asm volatile("s_waitcnt vmcnt(0)" ::: "memory");
        }
        __builtin_amdgcn_sched_barrier(0);
        __builtin_amdgcn_s_barrier();
        __builtin_amdgcn_sched_barrier(0);

        // ---- QK^T : 32 q-rows x 64 kv (q pre-scaled by 1/sqrt(d)) ----
        f32x4 sc[2][4];
#pragma unroll
        for (int mt = 0; mt < 2; ++mt)
#pragma unroll
            for (int nt = 0; nt < 4; ++nt) sc[mt][nt] = (f32x4){0.f, 0.f, 0.f, 0.f};
        __builtin_amdgcn_s_setprio(1);
#pragma unroll
        for (int ks = 0; ks < 4; ++ks) {
            short8 kfr[4];
#pragma unroll
            for (int nt = 0; nt < 4; ++nt) {
                int lin = ((nt * 16 + l15) << 8) + ks * 64 + l4 * 16;
                kfr[nt] = *(const short8*)(Ks[cur] + (lin ^ (((lin >> 8) & 7) << 4)));
            }
#pragma unroll
            for (int mt = 0; mt < 2; ++mt)
#pragma unroll
                for (int nt = 0; nt < 4; ++nt)
                    sc[mt][nt] = __builtin_amdgcn_mfma_f32_16x16x32_bf16(qf[mt][ks], kfr[nt], sc[mt][nt], 0, 0, 0);
        }
        __builtin_amdgcn_s_setprio(0);

        // ---- mask + row-max (shuffle reduce), defer-max decision ----
        float pmax[2][4];
        bool need = false;
#pragma unroll
        for (int mt = 0; mt < 2; ++mt)
#pragma unroll
            for (int j = 0; j < 4; ++j) {
                int srow = qrow0 + mt * 16 + l4 * 4 + j;
                int c = kv_start + t * 64 + l15;
                float v0 = (c      <= srow) ? sc[mt][0][j] : -1e30f;
                float v1 = (c + 16 <= srow) ? sc[mt][1][j] : -1e30f;
                float v2 = (c + 32 <= srow) ? sc[mt][2][j] : -1e30f;
                float v3 = (c + 48 <= srow) ? sc[mt][3][j] : -1e30f;
                sc[mt][0][j] = v0; sc[mt][1][j] = v1; sc[mt][2][j] = v2; sc[mt][3][j] = v3;
                float mx = fmaxf(fmaxf(v0, v1), fmaxf(v2, v3));
                mx = fmaxf(mx, __shfl_xor(mx, 1));
                mx = fmaxf(mx, __shfl_xor(mx, 2));
                mx = fmaxf(mx, __shfl_xor(mx, 4));
                mx = fmaxf(mx, __shfl_xor(mx, 8));
                pmax[mt][j] = mx;
                need = need || (mx > m_run[mt][j] + 8.0f);
            }
        if (__any(need ? 1 : 0)) {
#pragma unroll
            for (int mt = 0; mt < 2; ++mt)
#pragma unroll
                for (int j = 0; j < 4; ++j) {
                    float mnew = fmaxf(m_run[mt][j], pmax[mt][j]);
                    float r = __expf(m_run[mt][j] - mnew);
                    m_run[mt][j] = mnew;
                    lsum[mt][j] *= r;
#pragma unroll
                    for (int dt = 0; dt < 8; ++dt) o[mt][dt][j] *= r;
                }
        }

        // ---- P = exp(S - m), write to swizzled Ps ----
#pragma unroll
        for (int mt = 0; mt < 2; ++mt)
#pragma unroll
            for (int j = 0; j < 4; ++j) {
                int prow = mt * 16 + l4 * 4 + j;
                int rb = prow << 7;
                int sw = (prow & 7) << 4;
#pragma unroll
                for (int nt = 0; nt < 4; ++nt) {
                    unsigned short pb = f2bf(__expf(sc[mt][nt][j] - m_run[mt][j]));
                    *(unsigned short*)(Ps[w] + ((rb + (l15 + nt * 16) * 2) ^ sw)) = pb;
                }
            }
        asm volatile("s_waitcnt lgkmcnt(0)" ::: "memory");
        __builtin_amdgcn_sched_barrier(0);

        // ---- PV + ones-column row-sum ----
        short8 pf[2][2];
#pragma unroll
        for (int mt = 0; mt < 2; ++mt)
#pragma unroll
            for (int k2 = 0; k2 < 2; ++k2) {
                int lin = ((mt * 16 + l15) << 7) + k2 * 64 + l4 * 16;
                pf[mt][k2] = *(const short8*)(Ps[w] + (lin ^ (((lin >> 7) & 7) << 4)));
            }
        __builtin_amdgcn_s_setprio(1);
#pragma unroll
        for (int k2 = 0; k2 < 2; ++k2)
#pragma unroll
            for (int mt = 0; mt < 2; ++mt)
                lsum[mt] = __builtin_amdgcn_mfma_f32_16x16x32_bf16(pf[mt][k2], onesv, lsum[mt], 0, 0, 0);
#pragma unroll
        for (int dt = 0; dt < 8; ++dt) {
#pragma unroll
            for (int k2 = 0; k2 < 2; ++k2) {
                int lin = ((dt * 16 + l15) << 7) + k2 * 64 + l4 * 16;
                short8 vf = *(const short8*)(Vs[cur] + (lin ^ (((lin >> 7) & 7) << 4)));
#pragma unroll
                for (int mt = 0; mt < 2; ++mt)
                    o[mt][dt] = __builtin_amdgcn_mfma_f32_16x16x32_bf16(pf[mt][k2], vf, o[mt][dt], 0, 0, 0);
            }
        }
        __builtin_amdgcn_s_setprio(0);
        __builtin_amdgcn_sched_barrier(0);
        __builtin_amdgcn_s_barrier();
        __builtin_amdgcn_sched_barrier(0);
    }

    // epilogue: write unnormalized bf16 partial + fp32 (m, l)
    unsigned short* Op = O_parts + (size_t)pidx * 16384;
#pragma unroll
    for (int mt = 0; mt < 2; ++mt)
#pragma unroll
        for (int j = 0; j < 4; ++j) {
            int rloc = w * 32 + mt * 16 + l4 * 4 + j;
#pragma unroll
            for (int dt = 0; dt < 8; ++dt)
                Op[rloc * 128 + dt * 16 + l15] = f2bf(o[mt][dt][j]);
            if (l15 == 0) {
                ml[(size_t)pidx * 256 + rloc] = m_run[mt][j];
                ml[(size_t)pidx * 256 + 128 + rloc] = lsum[mt][j];
            }
        }
}

// merge partials: ctx[qblk*128+row][h*128+d] = sum_s w_s O_s / sum_s w_s l_s
__global__ __launch_bounds__(256) void reduce_k(const unsigned short* __restrict__ Op,
                                                const float* __restrict__ ml,
                                                unsigned short* __restrict__ ctx) {
    int qblk = blockIdx.x, h = blockIdx.y;
    int ns = (qblk >> 2) + 1;
    int st;
    if (qblk < 4) st = qblk;
    else if (qblk < 8) st = 4 + 2 * (qblk - 4);
    else if (qblk < 12) st = 12 + 3 * (qblk - 8);
    else st = 24 + 4 * (qblk - 12);
    int p0 = h * 40 + st;
#pragma unroll
    for (int it = 0; it < 16; ++it) {
        int idx = it * 256 + threadIdx.x;
        int row = idx >> 5, dq = idx & 31;
        float mstar = -1e30f;
        for (int s = 0; s < ns; ++s)
            mstar = fmaxf(mstar, ml[(size_t)(p0 + s) * 256 + row]);
        f32x4 acc = (f32x4){0.f, 0.f, 0.f, 0.f};
        float lt = 0.f;
        for (int s = 0; s < ns; ++s) {
            float wgt = __expf(ml[(size_t)(p0 + s) * 256 + row] - mstar);
            lt += wgt * ml[(size_t)(p0 + s) * 256 + 128 + row];
            ushort4 ov = *(const ushort4*)(Op + (size_t)(p0 + s) * 16384 + row * 128 + dq * 4);
            acc[0] += bf2f(ov.x) * wgt;
            acc[1] += bf2f(ov.y) * wgt;
            acc[2] += bf2f(ov.z) * wgt;
            acc[3] += bf2f(ov.w) * wgt;
        }
        float inv = 1.0f / lt;
        int grow = qblk * 128 + row;
        ushort4 o4;
        o4.x = f2bf(acc[0] * inv);
        o4.y = f2bf(acc[1] * inv);
        o4.z = f2bf(acc[2] * inv);
        o4.w = f2bf(acc[3] * inv);
        *(ushort4*)(ctx + (size_t)grow * HDIM + h * 128 + dq * 4) = o4;
    }
}

// ---------- launcher ----------

extern "C" void kernel_launch(void* const* d_in, const int* in_sizes, int n_in,
                              void* d_out, int out_size, void* d_ws, size_t ws_size,
                              hipStream_t stream) {
    const float* hs = (const float*)d_in[0];
    const float* wqkv = (const float*)d_in[1];
    const float* wo = (const float*)d_in[2];
    const int* pos = (const int*)d_in[4];
    float* out = (float*)d_out;
    char* ws = (char*)d_ws;
    const size_t MB = 1024 * 1024;

    unsigned short* hs_b = (unsigned short*)(ws);             // 16 MiB
    unsigned short* wq_t = (unsigned short*)(ws + 16 * MB);   // 96 MiB  [12288][4096] (q/k cols permuted)
    unsigned short* wo_t = (unsigned short*)(ws + 112 * MB);  // 32 MiB  [4096][4096]
    unsigned short* qbuf = (unsigned short*)(ws + 144 * MB);  // 16 MiB  [NH][S][HD]
    unsigned short* kbuf = (unsigned short*)(ws + 160 * MB);  // 16 MiB
    unsigned short* vtb  = (unsigned short*)(ws + 176 * MB);  // 16 MiB  [NH][HD][S]
    unsigned short* ctx  = (unsigned short*)(ws + 192 * MB);  // 16 MiB  [S][H]
    float* ctab = (float*)(ws + 208 * MB);                    // 512 KiB
    float* stab = (float*)(ws + 209 * MB);                    // 512 KiB
    // flash partials overlay the wq_t region (dead after gemm1; stream-ordered)
    unsigned short* O_parts = (unsigned short*)(ws + 16 * MB);  // 1280*16384*2B = 40 MiB
    float* ml_buf = (float*)(ws + 96 * MB);                     // 1280*256*4B = 1.25 MiB

    cvt_hs_k<<<(S_LEN * HDIM / 4 + 255) / 256, 256, 0, stream>>>(hs, hs_b, S_LEN * HDIM / 4);
    tconv_k<true><<<dim3(N_QKV / 64, HDIM / 64), 256, 0, stream>>>(wqkv, wq_t, HDIM, N_QKV);
    tconv_k<false><<<dim3(HDIM / 64, HDIM / 64), 256, 0, stream>>>(wo, wo_t, HDIM, HDIM);
    rope_tab_k<<<(S_LEN * 64) / 256, 256, 0, stream>>>(pos, ctab, stab);
    gemm1_k<<<dim3(N_QKV / 128, S_LEN / 128), 256, 0, stream>>>(hs_b, wq_t, ctab, stab, qbuf, kbuf, vtb);
    flash_k<<<dim3(40, NHEADS), 256, 0, stream>>>(qbuf, kbuf, vtb, O_parts, ml_buf);
    reduce_k<<<dim3(S_LEN / 128, NHEADS), 256, 0, stream>>>(O_parts, ml_buf, ctx);
    gemm2_k<<<dim3(HDIM / 128, S_LEN / 128), 256, 0, stream>>>(ctx, wo_t, out);
}